// Round 5
// baseline (390.529 us; speedup 1.0000x reference)
//
#include <hip/hip_runtime.h>

// RT-DETRv2 multiscale deformable attention, MI355X/gfx950.
// B=16, Q=300, S=8400 (80x80+40x40+20x20), D=256, H=8, HD=32, L=3, P=4, LP=12.
// Inputs fp32, output fp32 (verified; absmax 1.2e-3 vs thr 2.7e-3).
//
//   K0 prep:      pre-swizzle weights fp32->bf16 into B-fragment order
//   K1 gemm_value (R12): value = enc @ w_value^T + b -> ws bf16 [b][s][h][32]
//                 WHOLE B (128 KB) resident in LDS, loaded once (16 gload_lds
//                 rounds + ONE barrier). Then 8 independent wave-streams per
//                 block, each 32x128 tiles (acc[2][8]), 4-deep A prefetch,
//                 ZERO barriers in the main loop. Deletes the 2-barrier-per-
//                 kcb convoy (the measured disease) without exposing per-iter
//                 L2 latency (R10's mistake: B from L2 every kcb).
//   K2 proj_gemm: MFMA logits + fused softmax/loc -> ws attnw/locw fp32
//   K3 sample:    4 rq/block, 8B ushort4 gathers (4 ch/lane)
//   K4 gemm_nt:   out = sampled @ w_out^T + b_out -> d_out fp32 (col-split 150)
//
// Measured laws so far:
//  - acc > 16 f32x4/wave (RPW=2: 276 regs) -> 1 wave/SIMD -> 83->121/137 us. Never.
//  - K1 2-barrier LDS skeleton = 82.4 us FLOOR of that skeleton; R8 vmcnt(4)
//    85.7, R9 cvtpk 88.9, R10 L2-direct 112. All pipes idle (MFMA 8%, VALU
//    24%, HBM 31%) -> convoy/latency bound, not pipe bound.
//  - Inputs+ws are L3-resident across iterations (R10 FETCH 68.8MB < A size).
//  - cvtpk halves VALUBusy, zero time change -> VALU never on critical path.
//  - total - K1 ~= 206-216 us all rounds; K3 4x-vmem cut bought ~2 us ->
//    non-K1 kernels small/latency-ish; K1 is the controllable mass.

typedef __attribute__((ext_vector_type(8))) short short8;   // MFMA A/B frag (8 bf16)
typedef __attribute__((ext_vector_type(4))) short short4v;  // 4 bf16 (8B store)
typedef __attribute__((ext_vector_type(4))) float f32x4;    // MFMA accumulator

__device__ __forceinline__ unsigned short f2bf(float f) {   // fp32 -> bf16 RTNE
    union { float f; unsigned int i; } v; v.f = f;
    unsigned int r = v.i + 0x7FFFu + ((v.i >> 16) & 1u);
    return (unsigned short)(r >> 16);
}
__device__ __forceinline__ float bf2f(unsigned short u) {
    union { unsigned int i; float f; } v;
    v.i = ((unsigned int)u) << 16;
    return v.f;
}
__device__ __forceinline__ short8 cvt8(const float* p) {
    f32x4 x = *(const f32x4*)p;
    f32x4 y = *(const f32x4*)(p + 4);
    short8 r;
#pragma unroll
    for (int q = 0; q < 4; ++q) {
        r[q]     = (short)f2bf(x[q]);
        r[q + 4] = (short)f2bf(y[q]);
    }
    return r;
}
__device__ __forceinline__ short8 pack8(f32x4 x, f32x4 y) {  // regs -> bf16 frag
    short8 r;
#pragma unroll
    for (int q = 0; q < 4; ++q) {
        r[q]     = (short)f2bf(x[q]);
        r[q + 4] = (short)f2bf(y[q]);
    }
    return r;
}
__device__ __forceinline__ void barrier_lgkm() {
    asm volatile("s_waitcnt lgkmcnt(0)\n\ts_barrier" ::: "memory");
}
// async global->LDS, 16B per lane; LDS dest = wave-uniform base + lane*16
__device__ __forceinline__ void gload_lds16(const void* g, void* l) {
    __builtin_amdgcn_global_load_lds(
        (const __attribute__((address_space(1))) void*)g,
        (__attribute__((address_space(3))) void*)l, 16, 0, 0);
}

// ---- K0: pre-swizzle weights into B-fragment order (bf16) ------------------
// Slot s = kcb*1024 + tile*64 + fragLane holds
// W[n = tile*16 + (fl&15)][kcb*32 + (fl>>4)*8 .. +8).  Proj W: 18 n-tiles
// (288 rows = w_off ++ w_attn), 1152 slots/kcb.
__global__ __launch_bounds__(256) void prep_kernel(
    const float* __restrict__ wv, const float* __restrict__ wo,
    const float* __restrict__ w_off, const float* __restrict__ w_attn,
    short8* __restrict__ wv_s, short8* __restrict__ wo_s, short8* __restrict__ wp_s)
{
    const int blk = blockIdx.x, tid = threadIdx.x;
    if (blk < 64) {
        const float* W = (blk < 32) ? wv : wo;
        short8* out    = (blk < 32) ? wv_s : wo_s;
        int s   = ((blk & 31) << 8) + tid;
        int kcb = s >> 10, sl = s & 1023;
        int n = ((sl >> 6) << 4) + (sl & 15);
        int k = (kcb << 5) + (((sl >> 4) & 3) << 3);
        out[s] = cvt8(W + n * 256 + k);
    } else {
        int s   = ((blk - 64) << 8) + tid;
        int kcb = s / 1152, sl = s - kcb * 1152;
        int n = ((sl >> 6) << 4) + (sl & 15);
        int k = (kcb << 5) + (((sl >> 4) & 3) << 3);
        const float* p = (n < 192) ? (w_off + (size_t)n * 256 + k)
                                   : (w_attn + (size_t)(n - 192) * 256 + k);
        wp_s[s] = cvt8(p);
    }
}

// ---- K1 (R12): C[134400 x 256] = A @ W^T + bias, B fully LDS-resident ------
// Grid 256 x 512 threads (8 waves, 2/SIMD, 1 block/CU at 128 KB LDS).
// Prologue: whole pre-swizzled B -> LDS, one barrier. Main loop: wave-
// independent streams; wave w: col-half ch=w&1, stream st=blk*4+(w>>1);
// tiles of 32 rows, grid-stride 1024 over 4200 tiles. Per kcb: 4 A-loads
// (4-deep rolling prefetch), 2 pack8, 8 ds_read_b128, 16 MFMA. No barriers.
// Fragment math identical to the verified gemm128 (same Wswz slots, same
// C/D mapping) -> numerics unchanged.
__global__ __launch_bounds__(512) void gemm_value(
    const float* __restrict__ A,
    const short8* __restrict__ Wswz,
    const float* __restrict__ bias,
    unsigned short* __restrict__ C)
{
    __shared__ short8 lb[8192];   // 128 KiB: FULL B (256x256 bf16), swizzled
    const int tid  = threadIdx.x;
    const int wave = tid >> 6;
    const int lane = tid & 63;

    // prologue: contiguous copy, slots [r*512 + wave*64, +64) per round
#pragma unroll
    for (int r = 0; r < 16; ++r)
        gload_lds16(Wswz + (r << 9) + (wave << 6) + lane,
                    lb   + (r << 9) + (wave << 6));
    asm volatile("s_waitcnt vmcnt(0)" ::: "memory");
    __syncthreads();

    const int ch  = wave & 1;                         // col half (128 cols)
    const int st  = (blockIdx.x << 2) + (wave >> 1);  // stream 0..1023
    const int rlo = lane & 15;
    const int kq  = (lane >> 4) << 3;

    for (int tile = st; tile < 4200; tile += 1024) {
        const float* pa0 = A + (size_t)((tile << 5) + rlo) * 256 + kq;
        const float* pa1 = pa0 + 16 * 256;

        f32x4 acc[2][8];
#pragma unroll
        for (int i = 0; i < 2; ++i)
#pragma unroll
            for (int j = 0; j < 8; ++j) acc[i][j] = (f32x4){0.f, 0.f, 0.f, 0.f};

        // 4-deep rolling A prefetch: buf p holds kcb = (issue order)
        f32x4 a0[4][2], a1[4][2];
#pragma unroll
        for (int p = 0; p < 4; ++p) {
            a0[p][0] = *(const f32x4*)(pa0 + (p << 5));
            a0[p][1] = *(const f32x4*)(pa0 + (p << 5) + 4);
            a1[p][0] = *(const f32x4*)(pa1 + (p << 5));
            a1[p][1] = *(const f32x4*)(pa1 + (p << 5) + 4);
        }

#pragma unroll
        for (int kcb = 0; kcb < 8; ++kcb) {
            const int p = kcb & 3;
            short8 af0 = pack8(a0[p][0], a0[p][1]);
            short8 af1 = pack8(a1[p][0], a1[p][1]);
            if (kcb < 4) {                            // refill buf with kcb+4
                const int ko = (kcb + 4) << 5;
                a0[p][0] = *(const f32x4*)(pa0 + ko);
                a0[p][1] = *(const f32x4*)(pa0 + ko + 4);
                a1[p][0] = *(const f32x4*)(pa1 + ko);
                a1[p][1] = *(const f32x4*)(pa1 + ko + 4);
            }
            const short8* bb = lb + (kcb << 10) + (ch << 9) + lane;
#pragma unroll
            for (int j = 0; j < 8; ++j) {
                short8 bf = bb[(size_t)(j << 6)];
                acc[0][j] = __builtin_amdgcn_mfma_f32_16x16x32_bf16(af0, bf, acc[0][j], 0, 0, 0);
                acc[1][j] = __builtin_amdgcn_mfma_f32_16x16x32_bf16(af1, bf, acc[1][j], 0, 0, 0);
            }
        }

        // epilogue: D row = tile*32 + i*16 + (lane>>4)*4 + r,
        //           col = ch*128 + j*16 + (lane&15)
        const int rsub = (lane >> 4) << 2;
#pragma unroll
        for (int i = 0; i < 2; ++i) {
            const int rb = (tile << 5) + (i << 4) + rsub;
#pragma unroll
            for (int j = 0; j < 8; ++j) {
                const int n = (ch << 7) + (j << 4) + rlo;
                const float bv = bias[n];
#pragma unroll
                for (int r = 0; r < 4; ++r)
                    C[(size_t)(rb + r) * 256 + n] = f2bf(acc[i][j][r] + bv);
            }
        }
    }
}

// ---- K4: small-M GEMM, col-split (grid 150, 64 rows x 128 cols/block) ------
template <bool A_BF16, bool OUT_BF16>
__global__ __launch_bounds__(256) void gemm_nt(
    const void* __restrict__ Av,
    const short8* __restrict__ Wswz,
    const float* __restrict__ bias,
    void* __restrict__ Cv)
{
    __shared__ short8 lb[1024];                  // 16 KiB: one col-half, 2 kcb
    const int tid  = threadIdx.x;
    const int wave = tid >> 6;
    const int lane = tid & 63;
    const int row0 = (blockIdx.x >> 1) * 64 + wave * 16;
    const int colt = blockIdx.x & 1;

    f32x4 acc[8];
#pragma unroll
    for (int t = 0; t < 8; ++t) acc[t] = (f32x4){0.f, 0.f, 0.f, 0.f};

    const int am = row0 + (lane & 15);
    const int kq = (lane >> 4) << 3;

    const unsigned short* Ab = (const unsigned short*)Av;
    const float*          Af = (const float*)Av;

    short8 acur[2], anext[2];
#pragma unroll
    for (int kk = 0; kk < 2; ++kk) {
        if (A_BF16) acur[kk] = *(const short8*)(Ab + (size_t)am * 256 + (kk << 5) + kq);
        else        acur[kk] = cvt8(Af + (size_t)am * 256 + (kk << 5) + kq);
    }

    for (int st = 0; st < 4; ++st) {
        barrier_lgkm();
        // stage this col-half's 8 n-tiles for kcb = st*2, st*2+1 (1024 slots)
#pragma unroll
        for (int i = 0; i < 4; ++i) {
            int s  = tid + (i << 8);             // [0,1024)
            int kk = s >> 9, r = s & 511;
            lb[s] = Wswz[(((st << 1) + kk) << 10) + (colt << 9) + r];
        }
        barrier_lgkm();

        if (st < 3) {
            int kc = (st + 1) << 6;
#pragma unroll
            for (int kk = 0; kk < 2; ++kk) {
                if (A_BF16) anext[kk] = *(const short8*)(Ab + (size_t)am * 256 + kc + (kk << 5) + kq);
                else        anext[kk] = cvt8(Af + (size_t)am * 256 + kc + (kk << 5) + kq);
            }
        }

#pragma unroll
        for (int t = 0; t < 8; ++t) {
            short8 b0 = lb[t * 64 + lane];
            acc[t] = __builtin_amdgcn_mfma_f32_16x16x32_bf16(acur[0], b0, acc[t], 0, 0, 0);
            short8 b1 = lb[512 + t * 64 + lane];
            acc[t] = __builtin_amdgcn_mfma_f32_16x16x32_bf16(acur[1], b1, acc[t], 0, 0, 0);
        }
        acur[0] = anext[0];
        acur[1] = anext[1];
    }

    const int ncol = lane & 15;
    const int rb   = row0 + ((lane >> 4) << 2);
#pragma unroll
    for (int t = 0; t < 8; ++t) {
        int n = (colt << 7) + (t << 4) + ncol;
        float bv = bias[n];
#pragma unroll
        for (int r = 0; r < 4; ++r) {
            float v = acc[t][r] + bv;
            if (OUT_BF16)
                ((unsigned short*)Cv)[(size_t)(rb + r) * 256 + n] = f2bf(v);
            else
                ((float*)Cv)[(size_t)(rb + r) * 256 + n] = v;
        }
    }
}

// ---- K2: proj logits (MFMA) + fused softmax + sample locations -------------
#define LGS 296   // padded LDS row stride (floats)
__global__ __launch_bounds__(256) void proj_gemm(
    const float* __restrict__ hidden,
    const short8* __restrict__ Wswz,
    const float* __restrict__ b_off, const float* __restrict__ b_attn,
    const float* __restrict__ refp,
    float* __restrict__ attnw, float* __restrict__ locw)
{
    __shared__ char smem[32 * LGS * 4];
    short8* lb = (short8*)smem;
    float*  lg = (float*)smem;

    const int tid  = threadIdx.x;
    const int wave = tid >> 6;
    const int lane = tid & 63;
    const int rq0  = blockIdx.x * 32;
    const int rg   = wave >> 1;
    const int ts   = (wave & 1) * 9;
    const int row0 = rq0 + rg * 16;

    f32x4 acc[9];
#pragma unroll
    for (int t = 0; t < 9; ++t) acc[t] = (f32x4){0.f, 0.f, 0.f, 0.f};

    const int am = row0 + (lane & 15);
    const int kq = (lane >> 4) << 3;

    for (int kcb = 0; kcb < 8; ++kcb) {
        __syncthreads();
#pragma unroll
        for (int i = 0; i < 5; ++i) {
            int s = tid + (i << 8);
            if (s < 1152) lb[s] = Wswz[kcb * 1152 + s];
        }
        __syncthreads();

        short8 a = cvt8(hidden + (size_t)am * 256 + (kcb << 5) + kq);
#pragma unroll
        for (int t = 0; t < 9; ++t)
            acc[t] = __builtin_amdgcn_mfma_f32_16x16x32_bf16(a, lb[(ts + t) * 64 + lane], acc[t], 0, 0, 0);
    }

    __syncthreads();
    const int ncol = lane & 15;
    const int rb   = rg * 16 + ((lane >> 4) << 2);
#pragma unroll
    for (int t = 0; t < 9; ++t) {
        int n = (ts + t) * 16 + ncol;
        float bv = (n < 192) ? b_off[n] : b_attn[n - 192];
#pragma unroll
        for (int r = 0; r < 4; ++r)
            lg[(rb + r) * LGS + n] = acc[t][r] + bv;
    }
    __syncthreads();

    {   // softmax: 32 rows x 8 heads, one per thread
        int r = tid >> 3, h = tid & 7;
        const float* lrow = lg + r * LGS + 192 + h * 12;
        float m = -1e30f;
#pragma unroll
        for (int p = 0; p < 12; ++p) m = fmaxf(m, lrow[p]);
        float e[12], sum = 0.f;
#pragma unroll
        for (int p = 0; p < 12; ++p) { e[p] = __expf(lrow[p] - m); sum += e[p]; }
        float inv = 1.f / sum;
        float* ao = attnw + (size_t)(rq0 + r) * 96 + h * 12;
#pragma unroll
        for (int p = 0; p < 12; ++p) ao[p] = e[p] * inv;
    }
    if (tid < 192) {   // loc = ref_xy + logit*0.125*ref_wh
        int xy = tid & 1;
        for (int r = 0; r < 32; ++r) {
            int rq = rq0 + r;
            float rc  = refp[(size_t)rq * 4 + xy];
            float rwh = refp[(size_t)rq * 4 + 2 + xy];
            locw[(size_t)rq * 192 + tid] = rc + lg[r * LGS + tid] * 0.125f * rwh;
        }
    }
}

// ---- K3: deformable bilinear sampling (4 rq/block, 8B gathers) -------------
__global__ __launch_bounds__(256) void sample_kernel(
    const unsigned short* __restrict__ value,   // bf16 [b][s][h][32]
    const float* __restrict__ attnw, const float* __restrict__ locw,
    unsigned short* __restrict__ sampled)       // bf16 [rq][256]
{
    const int rq0 = blockIdx.x << 2;
    const int tid = threadIdx.x;

    __shared__ int4   soff[4][96];
    __shared__ float4 swt[4][96];

    // setup: 384 items (4 rq x 96 (h,lp)) across 256 threads
    for (int it = tid; it < 384; it += 256) {
        int rsub = it / 96;
        int idx  = it - rsub * 96;
        int rq   = rq0 + rsub;
        int b    = rq / 300;
        int h  = idx / 12, lp = idx - h * 12;
        int l  = lp >> 2;
        int Wl = (l == 0) ? 80 : (l == 1) ? 40 : 20;        // H == W per level
        int s0 = (l == 0) ? 0  : (l == 1) ? 6400 : 8000;
        float lx = locw[(size_t)rq * 192 + h * 24 + lp * 2];
        float ly = locw[(size_t)rq * 192 + h * 24 + lp * 2 + 1];
        float aw = attnw[(size_t)rq * 96 + h * 12 + lp];
        float gx = lx * (float)Wl - 0.5f;
        float gy = ly * (float)Wl - 0.5f;
        float x0f = floorf(gx), y0f = floorf(gy);
        int   x0 = (int)x0f,   y0 = (int)y0f;
        float wx1 = gx - x0f, wx0 = 1.f - wx1;
        float wy1 = gy - y0f, wy0 = 1.f - wy1;
        int4 of; float4 wt;
#pragma unroll
        for (int j = 0; j < 4; ++j) {
            int x = x0 + (j & 1), y = y0 + (j >> 1);
            bool ok = (x >= 0) & (x < Wl) & (y >= 0) & (y < Wl);
            int idx2 = ok ? (((b * 8400 + s0 + y * Wl + x) * 8 + h) * 32) : 0;
            float w = ok ? aw * ((j & 1) ? wx1 : wx0) * ((j >> 1) ? wy1 : wy0) : 0.f;
            ((int*)&of)[j] = idx2;
            ((float*)&wt)[j] = w;
        }
        soff[rsub][idx] = of;
        swt[rsub][idx]  = wt;
    }
    __syncthreads();

    const int rsub = tid >> 6;
    const int lane = tid & 63;
    const int h    = lane >> 3;
    const int cq   = (lane & 7) << 2;
    const int rq   = rq0 + rsub;

    float acc0 = 0.f, acc1 = 0.f, acc2 = 0.f, acc3 = 0.f;
    const int base = h * 12;
#pragma unroll
    for (int lp = 0; lp < 12; ++lp) {
        int4   of = soff[rsub][base + lp];
        float4 wt = swt[rsub][base + lp];
#pragma unroll
        for (int j = 0; j < 4; ++j) {
            int   o = ((const int*)&of)[j];
            float w = ((const float*)&wt)[j];
            uint2 u = *(const uint2*)(value + o + cq);     // 4 bf16 channels
            union { unsigned int i; float f; } c0, c1, c2, c3;
            c0.i = u.x << 16; c1.i = u.x & 0xFFFF0000u;
            c2.i = u.y << 16; c3.i = u.y & 0xFFFF0000u;
            acc0 += w * c0.f; acc1 += w * c1.f;
            acc2 += w * c2.f; acc3 += w * c3.f;
        }
    }
    short4v out;
    out[0] = (short)f2bf(acc0);
    out[1] = (short)f2bf(acc1);
    out[2] = (short)f2bf(acc2);
    out[3] = (short)f2bf(acc3);
    *(short4v*)(sampled + (size_t)rq * 256 + h * 32 + cq) = out;
}

extern "C" void kernel_launch(void* const* d_in, const int* in_sizes, int n_in,
                              void* d_out, int out_size, void* d_ws, size_t ws_size,
                              hipStream_t stream)
{
    const float* hidden  = (const float*)d_in[0];
    const float* enc     = (const float*)d_in[1];
    const float* refp    = (const float*)d_in[2];
    const float* w_value = (const float*)d_in[3];
    const float* b_value = (const float*)d_in[4];
    const float* w_off   = (const float*)d_in[5];
    const float* b_off   = (const float*)d_in[6];
    const float* w_attn  = (const float*)d_in[7];
    const float* b_attn  = (const float*)d_in[8];
    const float* w_out   = (const float*)d_in[9];
    const float* b_out   = (const float*)d_in[10];

    // ws layout: value 68,812,800 | sampled 2,457,600 | attnw 1,843,200 |
    // locw 3,686,400 | wv_swz 131,072 | wo_swz 131,072 | wp_swz 147,456
    char* ws = (char*)d_ws;
    unsigned short* value   = (unsigned short*)ws;
    unsigned short* sampled = (unsigned short*)(ws + 68812800);
    float*          attnw   = (float*)(ws + 71270400);
    float*          locw    = (float*)(ws + 73113600);
    short8*         wv_swz  = (short8*)(ws + 76800000);
    short8*         wo_swz  = (short8*)(ws + 76931072);
    short8*         wp_swz  = (short8*)(ws + 77062144);

    prep_kernel<<<100, 256, 0, stream>>>(w_value, w_out, w_off, w_attn,        // K0
                                         wv_swz, wo_swz, wp_swz);
    gemm_value<<<256, 512, 0, stream>>>(enc, wv_swz, b_value, value);          // K1
    proj_gemm<<<150, 256, 0, stream>>>(hidden, wp_swz, b_off, b_attn,          // K2
                                       refp, attnw, locw);
    sample_kernel<<<1200, 256, 0, stream>>>(value, attnw, locw, sampled);      // K3
    gemm_nt<true, false><<<150, 256, 0, stream>>>(sampled, wo_swz, b_out,      // K4
                                                  d_out);
}

// Round 6
// 280.322 us; speedup vs baseline: 1.3931x; 1.3931x over previous
//
#include <hip/hip_runtime.h>

// RT-DETRv2 multiscale deformable attention, MI355X/gfx950.
// B=16, Q=300, S=8400 (80x80+40x40+20x20), D=256, H=8, HD=32, L=3, P=4, LP=12.
// Inputs fp32, output fp32 (verified; absmax 1.2e-3 vs thr 2.7e-3).
//
//   K0 prep:      pre-swizzle weights fp32->bf16 into B-fragment order
//   K1 gemm128:   value = enc @ w_value^T + b -> ws bf16 [b][s][h][32]
//                 (round-0 structure, 82-84 us: STRUCTURALLY CLOSED, see laws)
//   K2 proj_gemm (R13): grid 300, 16 q/block; B direct from L2 (no LDS, no
//                 barriers in GEMM); N-split {5,5,4,4} tiles/wave; LDS only
//                 for 19KB logits exchange + softmax/loc epilogue.
//   K3 sample:    4 rq/block, 8B ushort4 gathers (4 ch/lane)
//   K4 out_gemm (R13): grid 300, 16 rows/block, 4 tiles/wave, LDS-FREE,
//                 barrier-free, direct-B, fully unrolled.
//
// Measured laws so far:
//  - acc > 16 f32x4/wave (RPW=2: 276 regs) -> 1 wave/SIMD -> 83->121/137 us. Never.
//  - K1 CLOSED at ~83 us: 2-barrier 16KB-LDS skeleton (~3 blk/CU TLP) beats
//    every variant tried: R8 vmcnt(4) 85.7, R9 cvtpk 88.9 (occ drop), R10
//    L2-direct-B 112 (per-iter L2 latency), R12 B-in-LDS-128KB 177 (1 blk/CU,
//    FETCH 212MB thrash, WRITE 2x from drifting partial-line stores).
//  - TLP (blocks/CU) dominates intra-wave scheduling at this problem size.
//  - Inputs+ws are L3-resident across iterations (R10 FETCH 68.8MB < A size).
//  - cvtpk halves VALUBusy, zero time change -> VALU never on critical path.
//  - total - K1 ~= 206 us all rounds; no non-K1 kernel ever in top-5 (<82 us
//    each). K2/K4: 0.6 blk/CU + 8x2-barrier staged rounds = convoy disease
//    at zero occupancy -> this round's target.

typedef __attribute__((ext_vector_type(8))) short short8;   // MFMA A/B frag (8 bf16)
typedef __attribute__((ext_vector_type(4))) short short4v;  // 4 bf16 (8B store)
typedef __attribute__((ext_vector_type(4))) float f32x4;    // MFMA accumulator

__device__ __forceinline__ unsigned short f2bf(float f) {   // fp32 -> bf16 RTNE
    union { float f; unsigned int i; } v; v.f = f;
    unsigned int r = v.i + 0x7FFFu + ((v.i >> 16) & 1u);
    return (unsigned short)(r >> 16);
}
__device__ __forceinline__ float bf2f(unsigned short u) {
    union { unsigned int i; float f; } v;
    v.i = ((unsigned int)u) << 16;
    return v.f;
}
__device__ __forceinline__ short8 cvt8(const float* p) {
    f32x4 x = *(const f32x4*)p;
    f32x4 y = *(const f32x4*)(p + 4);
    short8 r;
#pragma unroll
    for (int q = 0; q < 4; ++q) {
        r[q]     = (short)f2bf(x[q]);
        r[q + 4] = (short)f2bf(y[q]);
    }
    return r;
}
__device__ __forceinline__ void barrier_lgkm() {
    asm volatile("s_waitcnt lgkmcnt(0)\n\ts_barrier" ::: "memory");
}

// ---- K0: pre-swizzle weights into B-fragment order (bf16) ------------------
// Slot s = kcb*1024 + tile*64 + fragLane holds
// W[n = tile*16 + (fl&15)][kcb*32 + (fl>>4)*8 .. +8).  Proj W: 18 n-tiles
// (288 rows = w_off ++ w_attn), 1152 slots/kcb.
__global__ __launch_bounds__(256) void prep_kernel(
    const float* __restrict__ wv, const float* __restrict__ wo,
    const float* __restrict__ w_off, const float* __restrict__ w_attn,
    short8* __restrict__ wv_s, short8* __restrict__ wo_s, short8* __restrict__ wp_s)
{
    const int blk = blockIdx.x, tid = threadIdx.x;
    if (blk < 64) {
        const float* W = (blk < 32) ? wv : wo;
        short8* out    = (blk < 32) ? wv_s : wo_s;
        int s   = ((blk & 31) << 8) + tid;
        int kcb = s >> 10, sl = s & 1023;
        int n = ((sl >> 6) << 4) + (sl & 15);
        int k = (kcb << 5) + (((sl >> 4) & 3) << 3);
        out[s] = cvt8(W + n * 256 + k);
    } else {
        int s   = ((blk - 64) << 8) + tid;
        int kcb = s / 1152, sl = s - kcb * 1152;
        int n = ((sl >> 6) << 4) + (sl & 15);
        int k = (kcb << 5) + (((sl >> 4) & 3) << 3);
        const float* p = (n < 192) ? (w_off + (size_t)n * 256 + k)
                                   : (w_attn + (size_t)(n - 192) * 256 + k);
        wp_s[s] = cvt8(p);
    }
}

// ---- K1: C[M x 256] = A[M x 256] @ W^T + bias, 128x128 tiles ---------------
// Round-0 structure (82.4 us, CLOSED). Grid (M/128)*2; blockIdx>>1 = row
// block, &1 = col half. 4 waves = 2x2 quadrants of 64x64.
__global__ __launch_bounds__(256) void gemm128(
    const float* __restrict__ A,
    const short8* __restrict__ Wswz,
    const float* __restrict__ bias,
    unsigned short* __restrict__ C)
{
    __shared__ short8 lb[1024];   // 16 KiB: A slots [0,512), B slots [512,1024)
    const int tid  = threadIdx.x;
    const int wave = tid >> 6;
    const int lane = tid & 63;
    const int row0 = (blockIdx.x >> 1) * 128;
    const int colt = blockIdx.x & 1;            // which 128-col half
    const int mq   = wave >> 1;                 // wave quadrant
    const int nq   = wave & 1;

    f32x4 acc[4][4];
#pragma unroll
    for (int i = 0; i < 4; ++i)
#pragma unroll
        for (int j = 0; j < 4; ++j) acc[i][j] = (f32x4){0.f, 0.f, 0.f, 0.f};

    // staging indices for this thread's 4 slots (2 A, 2 B)
    const int sa0 = tid, sa1 = tid + 256;       // A slots
    const int am0 = row0 + ((sa0 >> 6) << 4) + (sa0 & 15);
    const int ak0 = ((sa0 >> 4) & 3) << 3;
    const int am1 = row0 + ((sa1 >> 6) << 4) + (sa1 & 15);
    const int ak1 = ((sa1 >> 4) & 3) << 3;

    for (int kcb = 0; kcb < 8; ++kcb) {
        const int kc = kcb << 5;
        barrier_lgkm();
        // A tile: 512 slots in fragment order
        lb[sa0] = cvt8(A + (size_t)am0 * 256 + kc + ak0);
        lb[sa1] = cvt8(A + (size_t)am1 * 256 + kc + ak1);
        // B tile: contiguous 512-slot copy of this col-half's 8 n-tiles
        const short8* wsrc = Wswz + (kcb << 10) + (colt << 9);
        lb[512 + tid]       = wsrc[tid];
        lb[768 + tid]       = wsrc[tid + 256];
        barrier_lgkm();

        short8 af[4], bf[4];
#pragma unroll
        for (int i = 0; i < 4; ++i) af[i] = lb[((mq << 2) + i) * 64 + lane];
#pragma unroll
        for (int j = 0; j < 4; ++j) bf[j] = lb[512 + ((nq << 2) + j) * 64 + lane];
#pragma unroll
        for (int i = 0; i < 4; ++i)
#pragma unroll
            for (int j = 0; j < 4; ++j)
                acc[i][j] = __builtin_amdgcn_mfma_f32_16x16x32_bf16(af[i], bf[j], acc[i][j], 0, 0, 0);
    }

    // epilogue: D row = row0 + (mq*4+i)*16 + (lane>>4)*4 + r,
    //           col = colt*128 + (nq*4+j)*16 + (lane&15)
    const int ncol = lane & 15;
    const int rsub = (lane >> 4) << 2;
#pragma unroll
    for (int i = 0; i < 4; ++i) {
        const int rb = row0 + ((mq << 2) + i) * 16 + rsub;
#pragma unroll
        for (int j = 0; j < 4; ++j) {
            const int n = (colt << 7) + ((nq << 2) + j) * 16 + ncol;
            const float bv = bias[n];
#pragma unroll
            for (int r = 0; r < 4; ++r)
                C[(size_t)(rb + r) * 256 + n] = f2bf(acc[i][j][r] + bv);
        }
    }
}

// ---- K2 (R13): proj logits, barrier-free direct-B + fused softmax/loc ------
// Grid 300 x 256: 16 queries/block. Wave w owns n-tiles [ts, ts+tc):
// {0-4},{5-9},{10-13},{14-17}. Per kcb (fully unrolled): 1 cvt8 A + tc
// direct B loads (L2/L3-resident wp_s) + tc MFMA. No __syncthreads until
// the logits-LDS exchange. LDS = 16 x LGS floats (19 KB).
#define LGS 296   // padded LDS row stride (floats)
__global__ __launch_bounds__(256) void proj_gemm(
    const float* __restrict__ hidden,
    const short8* __restrict__ Wswz,
    const float* __restrict__ b_off, const float* __restrict__ b_attn,
    const float* __restrict__ refp,
    float* __restrict__ attnw, float* __restrict__ locw)
{
    __shared__ float lg[16 * LGS];

    const int tid  = threadIdx.x;
    const int wave = tid >> 6;
    const int lane = tid & 63;
    const int rq0  = blockIdx.x * 16;

    const int ts = (wave < 2) ? wave * 5 : 10 + ((wave - 2) << 2);
    const int tc = (wave < 2) ? 5 : 4;

    f32x4 acc[5];
#pragma unroll
    for (int t = 0; t < 5; ++t) acc[t] = (f32x4){0.f, 0.f, 0.f, 0.f};

    const int am = rq0 + (lane & 15);
    const int kq = (lane >> 4) << 3;

#pragma unroll
    for (int kcb = 0; kcb < 8; ++kcb) {
        short8 a = cvt8(hidden + (size_t)am * 256 + (kcb << 5) + kq);
        const short8* bb = Wswz + kcb * 1152 + (ts << 6) + lane;
#pragma unroll
        for (int t = 0; t < 5; ++t)
            if (t < tc)
                acc[t] = __builtin_amdgcn_mfma_f32_16x16x32_bf16(a, bb[t << 6], acc[t], 0, 0, 0);
    }

    // logits -> LDS (rows 0..15 of this block)
    const int ncol = lane & 15;
    const int rb   = (lane >> 4) << 2;
#pragma unroll
    for (int t = 0; t < 5; ++t) {
        if (t < tc) {
            int n = ((ts + t) << 4) + ncol;
            float bv = (n < 192) ? b_off[n] : b_attn[n - 192];
#pragma unroll
            for (int r = 0; r < 4; ++r)
                lg[(rb + r) * LGS + n] = acc[t][r] + bv;
        }
    }
    __syncthreads();

    if (tid < 128) {   // softmax: 16 rows x 8 heads, one per thread
        int r = tid >> 3, h = tid & 7;
        const float* lrow = lg + r * LGS + 192 + h * 12;
        float m = -1e30f;
#pragma unroll
        for (int p = 0; p < 12; ++p) m = fmaxf(m, lrow[p]);
        float e[12], sum = 0.f;
#pragma unroll
        for (int p = 0; p < 12; ++p) { e[p] = __expf(lrow[p] - m); sum += e[p]; }
        float inv = 1.f / sum;
        float* ao = attnw + (size_t)(rq0 + r) * 96 + h * 12;
#pragma unroll
        for (int p = 0; p < 12; ++p) ao[p] = e[p] * inv;
    }
    if (tid < 192) {   // loc = ref_xy + logit*0.125*ref_wh
        int xy = tid & 1;
#pragma unroll
        for (int r = 0; r < 16; ++r) {
            int rq = rq0 + r;
            float rc  = refp[(size_t)rq * 4 + xy];
            float rwh = refp[(size_t)rq * 4 + 2 + xy];
            locw[(size_t)rq * 192 + tid] = rc + lg[r * LGS + tid] * 0.125f * rwh;
        }
    }
}

// ---- K4 (R13): out = sampled @ w_out^T + b_out, LDS-free barrier-free ------
// Grid 300 x 256: 16 rows/block, wave w owns n-tiles [w*4, w*4+4).
// Per kcb (fully unrolled): 1 short8 A load + 4 direct B loads + 4 MFMA.
__global__ __launch_bounds__(256) void out_gemm(
    const unsigned short* __restrict__ Ab,     // sampled bf16 [4800][256]
    const short8* __restrict__ Wswz,
    const float* __restrict__ bias,
    float* __restrict__ Cv)
{
    const int tid  = threadIdx.x;
    const int wave = tid >> 6;
    const int lane = tid & 63;
    const int row0 = blockIdx.x * 16;

    f32x4 acc[4];
#pragma unroll
    for (int t = 0; t < 4; ++t) acc[t] = (f32x4){0.f, 0.f, 0.f, 0.f};

    const int am = row0 + (lane & 15);
    const int kq = (lane >> 4) << 3;

#pragma unroll
    for (int kcb = 0; kcb < 8; ++kcb) {
        short8 a = *(const short8*)(Ab + (size_t)am * 256 + (kcb << 5) + kq);
        const short8* bb = Wswz + (kcb << 10) + (wave << 8) + lane;
#pragma unroll
        for (int t = 0; t < 4; ++t)
            acc[t] = __builtin_amdgcn_mfma_f32_16x16x32_bf16(a, bb[t << 6], acc[t], 0, 0, 0);
    }

    const int ncol = lane & 15;
    const int rb   = row0 + ((lane >> 4) << 2);
#pragma unroll
    for (int t = 0; t < 4; ++t) {
        int n = (wave << 6) + (t << 4) + ncol;
        float bv = bias[n];
#pragma unroll
        for (int r = 0; r < 4; ++r)
            Cv[(size_t)(rb + r) * 256 + n] = acc[t][r] + bv;
    }
}

// ---- K3: deformable bilinear sampling (4 rq/block, 8B gathers) -------------
__global__ __launch_bounds__(256) void sample_kernel(
    const unsigned short* __restrict__ value,   // bf16 [b][s][h][32]
    const float* __restrict__ attnw, const float* __restrict__ locw,
    unsigned short* __restrict__ sampled)       // bf16 [rq][256]
{
    const int rq0 = blockIdx.x << 2;
    const int tid = threadIdx.x;

    __shared__ int4   soff[4][96];
    __shared__ float4 swt[4][96];

    // setup: 384 items (4 rq x 96 (h,lp)) across 256 threads
    for (int it = tid; it < 384; it += 256) {
        int rsub = it / 96;
        int idx  = it - rsub * 96;
        int rq   = rq0 + rsub;
        int b    = rq / 300;
        int h  = idx / 12, lp = idx - h * 12;
        int l  = lp >> 2;
        int Wl = (l == 0) ? 80 : (l == 1) ? 40 : 20;        // H == W per level
        int s0 = (l == 0) ? 0  : (l == 1) ? 6400 : 8000;
        float lx = locw[(size_t)rq * 192 + h * 24 + lp * 2];
        float ly = locw[(size_t)rq * 192 + h * 24 + lp * 2 + 1];
        float aw = attnw[(size_t)rq * 96 + h * 12 + lp];
        float gx = lx * (float)Wl - 0.5f;
        float gy = ly * (float)Wl - 0.5f;
        float x0f = floorf(gx), y0f = floorf(gy);
        int   x0 = (int)x0f,   y0 = (int)y0f;
        float wx1 = gx - x0f, wx0 = 1.f - wx1;
        float wy1 = gy - y0f, wy0 = 1.f - wy1;
        int4 of; float4 wt;
#pragma unroll
        for (int j = 0; j < 4; ++j) {
            int x = x0 + (j & 1), y = y0 + (j >> 1);
            bool ok = (x >= 0) & (x < Wl) & (y >= 0) & (y < Wl);
            int idx2 = ok ? (((b * 8400 + s0 + y * Wl + x) * 8 + h) * 32) : 0;
            float w = ok ? aw * ((j & 1) ? wx1 : wx0) * ((j >> 1) ? wy1 : wy0) : 0.f;
            ((int*)&of)[j] = idx2;
            ((float*)&wt)[j] = w;
        }
        soff[rsub][idx] = of;
        swt[rsub][idx]  = wt;
    }
    __syncthreads();

    const int rsub = tid >> 6;
    const int lane = tid & 63;
    const int h    = lane >> 3;
    const int cq   = (lane & 7) << 2;
    const int rq   = rq0 + rsub;

    float acc0 = 0.f, acc1 = 0.f, acc2 = 0.f, acc3 = 0.f;
    const int base = h * 12;
#pragma unroll
    for (int lp = 0; lp < 12; ++lp) {
        int4   of = soff[rsub][base + lp];
        float4 wt = swt[rsub][base + lp];
#pragma unroll
        for (int j = 0; j < 4; ++j) {
            int   o = ((const int*)&of)[j];
            float w = ((const float*)&wt)[j];
            uint2 u = *(const uint2*)(value + o + cq);     // 4 bf16 channels
            union { unsigned int i; float f; } c0, c1, c2, c3;
            c0.i = u.x << 16; c1.i = u.x & 0xFFFF0000u;
            c2.i = u.y << 16; c3.i = u.y & 0xFFFF0000u;
            acc0 += w * c0.f; acc1 += w * c1.f;
            acc2 += w * c2.f; acc3 += w * c3.f;
        }
    }
    short4v out;
    out[0] = (short)f2bf(acc0);
    out[1] = (short)f2bf(acc1);
    out[2] = (short)f2bf(acc2);
    out[3] = (short)f2bf(acc3);
    *(short4v*)(sampled + (size_t)rq * 256 + h * 32 + cq) = out;
}

extern "C" void kernel_launch(void* const* d_in, const int* in_sizes, int n_in,
                              void* d_out, int out_size, void* d_ws, size_t ws_size,
                              hipStream_t stream)
{
    const float* hidden  = (const float*)d_in[0];
    const float* enc     = (const float*)d_in[1];
    const float* refp    = (const float*)d_in[2];
    const float* w_value = (const float*)d_in[3];
    const float* b_value = (const float*)d_in[4];
    const float* w_off   = (const float*)d_in[5];
    const float* b_off   = (const float*)d_in[6];
    const float* w_attn  = (const float*)d_in[7];
    const float* b_attn  = (const float*)d_in[8];
    const float* w_out   = (const float*)d_in[9];
    const float* b_out   = (const float*)d_in[10];

    // ws layout: value 68,812,800 | sampled 2,457,600 | attnw 1,843,200 |
    // locw 3,686,400 | wv_swz 131,072 | wo_swz 131,072 | wp_swz 147,456
    char* ws = (char*)d_ws;
    unsigned short* value   = (unsigned short*)ws;
    unsigned short* sampled = (unsigned short*)(ws + 68812800);
    float*          attnw   = (float*)(ws + 71270400);
    float*          locw    = (float*)(ws + 73113600);
    short8*         wv_swz  = (short8*)(ws + 76800000);
    short8*         wo_swz  = (short8*)(ws + 76931072);
    short8*         wp_swz  = (short8*)(ws + 77062144);

    prep_kernel<<<100, 256, 0, stream>>>(w_value, w_out, w_off, w_attn,        // K0
                                         wv_swz, wo_swz, wp_swz);
    gemm128<<<2100, 256, 0, stream>>>(enc, wv_swz, b_value, value);            // K1
    proj_gemm<<<300, 256, 0, stream>>>(hidden, wp_swz, b_off, b_attn,          // K2
                                       refp, attnw, locw);
    sample_kernel<<<1200, 256, 0, stream>>>(value, attnw, locw, sampled);      // K3
    out_gemm<<<300, 256, 0, stream>>>(sampled, wo_swz, b_out, (float*)d_out);  // K4
}

// Round 7
// 280.265 us; speedup vs baseline: 1.3934x; 1.0002x over previous
//
#include <hip/hip_runtime.h>

// RT-DETRv2 multiscale deformable attention, MI355X/gfx950.
// B=16, Q=300, S=8400 (80x80+40x40+20x20), D=256, H=8, HD=32, L=3, P=4, LP=12.
// Inputs fp32, output fp32 (verified; absmax 1.2e-3 vs thr 2.7e-3).
//
//   K0 prep:      pre-swizzle weights fp32->bf16 into B-fragment order
//   K1 gemm128:   value = enc @ w_value^T + b -> ws bf16 [b][s][h][32]
//                 (round-0 structure, 82-84 us: STRUCTURALLY CLOSED, see laws)
//   K2 proj_gemm: grid 300, 16 q/block, direct-B, barrier-free GEMM,
//                 fused softmax/loc (R13)
//   K34 sample_out (R14): FUSED K3+K4. Phase A: corner-table + 8B ushort4
//                 gathers for 16 rq -> LDS (stride 264 bf16: A-frag ds_reads
//                 2-way bank-aliased = free). Phase B: out = sampled @ w_out^T
//                 + b_out, A-frags from LDS, 2 n-tiles/wave. Deletes one
//                 launch + the 2.4MB sampled global round-trip.
//
// Measured laws so far:
//  - acc > 16 f32x4/wave (RPW=2: 276 regs) -> 1 wave/SIMD -> 83->121/137 us. Never.
//  - K1 CLOSED at ~83 us: 2-barrier 16KB-LDS skeleton (~3 blk/CU TLP) beats
//    every variant tried: R8 vmcnt(4) 85.7, R9 cvtpk 88.9 (occ drop), R10
//    L2-direct-B 112 (per-iter L2 latency), R12 B-in-LDS-128KB 177 (1 blk/CU,
//    FETCH 212MB thrash, WRITE 2x partial-line). TLP > intra-wave scheduling.
//  - Inputs+ws are L3-resident across iterations (R10 FETCH 68.8MB < A size).
//  - cvtpk halves VALUBusy, zero time change -> VALU never on critical path.
//  - R13 K2/K4 de-convoy: -9.5 us (barrier-free direct-B at small grids).
//  - Rest-minus-kernels ~= 140 us CONSTANT across 7 rounds -> harness reset
//    overhead inside timed window (dozens of tiny memsets); uncontrollable.
//    Controllable surface: K1 (closed) + ~60 us of small kernels.

typedef __attribute__((ext_vector_type(8))) short short8;   // MFMA A/B frag (8 bf16)
typedef __attribute__((ext_vector_type(4))) short short4v;  // 4 bf16 (8B)
typedef __attribute__((ext_vector_type(4))) float f32x4;    // MFMA accumulator

__device__ __forceinline__ unsigned short f2bf(float f) {   // fp32 -> bf16 RTNE
    union { float f; unsigned int i; } v; v.f = f;
    unsigned int r = v.i + 0x7FFFu + ((v.i >> 16) & 1u);
    return (unsigned short)(r >> 16);
}
__device__ __forceinline__ float bf2f(unsigned short u) {
    union { unsigned int i; float f; } v;
    v.i = ((unsigned int)u) << 16;
    return v.f;
}
__device__ __forceinline__ short8 cvt8(const float* p) {
    f32x4 x = *(const f32x4*)p;
    f32x4 y = *(const f32x4*)(p + 4);
    short8 r;
#pragma unroll
    for (int q = 0; q < 4; ++q) {
        r[q]     = (short)f2bf(x[q]);
        r[q + 4] = (short)f2bf(y[q]);
    }
    return r;
}
__device__ __forceinline__ void barrier_lgkm() {
    asm volatile("s_waitcnt lgkmcnt(0)\n\ts_barrier" ::: "memory");
}

// ---- K0: pre-swizzle weights into B-fragment order (bf16) ------------------
// Slot s = kcb*1024 + tile*64 + fragLane holds
// W[n = tile*16 + (fl&15)][kcb*32 + (fl>>4)*8 .. +8).  Proj W: 18 n-tiles
// (288 rows = w_off ++ w_attn), 1152 slots/kcb.
__global__ __launch_bounds__(256) void prep_kernel(
    const float* __restrict__ wv, const float* __restrict__ wo,
    const float* __restrict__ w_off, const float* __restrict__ w_attn,
    short8* __restrict__ wv_s, short8* __restrict__ wo_s, short8* __restrict__ wp_s)
{
    const int blk = blockIdx.x, tid = threadIdx.x;
    if (blk < 64) {
        const float* W = (blk < 32) ? wv : wo;
        short8* out    = (blk < 32) ? wv_s : wo_s;
        int s   = ((blk & 31) << 8) + tid;
        int kcb = s >> 10, sl = s & 1023;
        int n = ((sl >> 6) << 4) + (sl & 15);
        int k = (kcb << 5) + (((sl >> 4) & 3) << 3);
        out[s] = cvt8(W + n * 256 + k);
    } else {
        int s   = ((blk - 64) << 8) + tid;
        int kcb = s / 1152, sl = s - kcb * 1152;
        int n = ((sl >> 6) << 4) + (sl & 15);
        int k = (kcb << 5) + (((sl >> 4) & 3) << 3);
        const float* p = (n < 192) ? (w_off + (size_t)n * 256 + k)
                                   : (w_attn + (size_t)(n - 192) * 256 + k);
        wp_s[s] = cvt8(p);
    }
}

// ---- K1: C[M x 256] = A[M x 256] @ W^T + bias, 128x128 tiles ---------------
// Round-0 structure (82.4 us, CLOSED). Grid (M/128)*2; blockIdx>>1 = row
// block, &1 = col half. 4 waves = 2x2 quadrants of 64x64.
__global__ __launch_bounds__(256) void gemm128(
    const float* __restrict__ A,
    const short8* __restrict__ Wswz,
    const float* __restrict__ bias,
    unsigned short* __restrict__ C)
{
    __shared__ short8 lb[1024];   // 16 KiB: A slots [0,512), B slots [512,1024)
    const int tid  = threadIdx.x;
    const int wave = tid >> 6;
    const int lane = tid & 63;
    const int row0 = (blockIdx.x >> 1) * 128;
    const int colt = blockIdx.x & 1;            // which 128-col half
    const int mq   = wave >> 1;                 // wave quadrant
    const int nq   = wave & 1;

    f32x4 acc[4][4];
#pragma unroll
    for (int i = 0; i < 4; ++i)
#pragma unroll
        for (int j = 0; j < 4; ++j) acc[i][j] = (f32x4){0.f, 0.f, 0.f, 0.f};

    // staging indices for this thread's 4 slots (2 A, 2 B)
    const int sa0 = tid, sa1 = tid + 256;       // A slots
    const int am0 = row0 + ((sa0 >> 6) << 4) + (sa0 & 15);
    const int ak0 = ((sa0 >> 4) & 3) << 3;
    const int am1 = row0 + ((sa1 >> 6) << 4) + (sa1 & 15);
    const int ak1 = ((sa1 >> 4) & 3) << 3;

    for (int kcb = 0; kcb < 8; ++kcb) {
        const int kc = kcb << 5;
        barrier_lgkm();
        // A tile: 512 slots in fragment order
        lb[sa0] = cvt8(A + (size_t)am0 * 256 + kc + ak0);
        lb[sa1] = cvt8(A + (size_t)am1 * 256 + kc + ak1);
        // B tile: contiguous 512-slot copy of this col-half's 8 n-tiles
        const short8* wsrc = Wswz + (kcb << 10) + (colt << 9);
        lb[512 + tid]       = wsrc[tid];
        lb[768 + tid]       = wsrc[tid + 256];
        barrier_lgkm();

        short8 af[4], bf[4];
#pragma unroll
        for (int i = 0; i < 4; ++i) af[i] = lb[((mq << 2) + i) * 64 + lane];
#pragma unroll
        for (int j = 0; j < 4; ++j) bf[j] = lb[512 + ((nq << 2) + j) * 64 + lane];
#pragma unroll
        for (int i = 0; i < 4; ++i)
#pragma unroll
            for (int j = 0; j < 4; ++j)
                acc[i][j] = __builtin_amdgcn_mfma_f32_16x16x32_bf16(af[i], bf[j], acc[i][j], 0, 0, 0);
    }

    // epilogue: D row = row0 + (mq*4+i)*16 + (lane>>4)*4 + r,
    //           col = colt*128 + (nq*4+j)*16 + (lane&15)
    const int ncol = lane & 15;
    const int rsub = (lane >> 4) << 2;
#pragma unroll
    for (int i = 0; i < 4; ++i) {
        const int rb = row0 + ((mq << 2) + i) * 16 + rsub;
#pragma unroll
        for (int j = 0; j < 4; ++j) {
            const int n = (colt << 7) + ((nq << 2) + j) * 16 + ncol;
            const float bv = bias[n];
#pragma unroll
            for (int r = 0; r < 4; ++r)
                C[(size_t)(rb + r) * 256 + n] = f2bf(acc[i][j][r] + bv);
        }
    }
}

// ---- K2: proj logits, barrier-free direct-B + fused softmax/loc ------------
// Grid 300 x 256: 16 queries/block. Wave w owns n-tiles [ts, ts+tc):
// {0-4},{5-9},{10-13},{14-17}. Per kcb (fully unrolled): 1 cvt8 A + tc
// direct B loads (L2/L3-resident wp_s) + tc MFMA. No __syncthreads until
// the logits-LDS exchange. LDS = 16 x LGS floats (19 KB).
#define LGS 296   // padded LDS row stride (floats)
__global__ __launch_bounds__(256) void proj_gemm(
    const float* __restrict__ hidden,
    const short8* __restrict__ Wswz,
    const float* __restrict__ b_off, const float* __restrict__ b_attn,
    const float* __restrict__ refp,
    float* __restrict__ attnw, float* __restrict__ locw)
{
    __shared__ float lg[16 * LGS];

    const int tid  = threadIdx.x;
    const int wave = tid >> 6;
    const int lane = tid & 63;
    const int rq0  = blockIdx.x * 16;

    const int ts = (wave < 2) ? wave * 5 : 10 + ((wave - 2) << 2);
    const int tc = (wave < 2) ? 5 : 4;

    f32x4 acc[5];
#pragma unroll
    for (int t = 0; t < 5; ++t) acc[t] = (f32x4){0.f, 0.f, 0.f, 0.f};

    const int am = rq0 + (lane & 15);
    const int kq = (lane >> 4) << 3;

#pragma unroll
    for (int kcb = 0; kcb < 8; ++kcb) {
        short8 a = cvt8(hidden + (size_t)am * 256 + (kcb << 5) + kq);
        const short8* bb = Wswz + kcb * 1152 + (ts << 6) + lane;
#pragma unroll
        for (int t = 0; t < 5; ++t)
            if (t < tc)
                acc[t] = __builtin_amdgcn_mfma_f32_16x16x32_bf16(a, bb[t << 6], acc[t], 0, 0, 0);
    }

    // logits -> LDS (rows 0..15 of this block)
    const int ncol = lane & 15;
    const int rb   = (lane >> 4) << 2;
#pragma unroll
    for (int t = 0; t < 5; ++t) {
        if (t < tc) {
            int n = ((ts + t) << 4) + ncol;
            float bv = (n < 192) ? b_off[n] : b_attn[n - 192];
#pragma unroll
            for (int r = 0; r < 4; ++r)
                lg[(rb + r) * LGS + n] = acc[t][r] + bv;
        }
    }
    __syncthreads();

    if (tid < 128) {   // softmax: 16 rows x 8 heads, one per thread
        int r = tid >> 3, h = tid & 7;
        const float* lrow = lg + r * LGS + 192 + h * 12;
        float m = -1e30f;
#pragma unroll
        for (int p = 0; p < 12; ++p) m = fmaxf(m, lrow[p]);
        float e[12], sum = 0.f;
#pragma unroll
        for (int p = 0; p < 12; ++p) { e[p] = __expf(lrow[p] - m); sum += e[p]; }
        float inv = 1.f / sum;
        float* ao = attnw + (size_t)(rq0 + r) * 96 + h * 12;
#pragma unroll
        for (int p = 0; p < 12; ++p) ao[p] = e[p] * inv;
    }
    if (tid < 192) {   // loc = ref_xy + logit*0.125*ref_wh
        int xy = tid & 1;
#pragma unroll
        for (int r = 0; r < 16; ++r) {
            int rq = rq0 + r;
            float rc  = refp[(size_t)rq * 4 + xy];
            float rwh = refp[(size_t)rq * 4 + 2 + xy];
            locw[(size_t)rq * 192 + tid] = rc + lg[r * LGS + tid] * 0.125f * rwh;
        }
    }
}

// ---- K34 (R14): fused sampling + output GEMM -------------------------------
// Grid 300 x 512 (8 waves): 16 rq/block.
// Phase A: corner tables for 16x96 points; wave w gathers rq {2w, 2w+1}
//   (h = lane>>3, cq = (lane&7)*4; 48 ushort4 8B gathers per rq) -> LDS
//   sampled[16][264] bf16 (stride 264 = +8 pad: A-frag ds_reads land 2-way
//   bank-aliased across 16 rows = free).
// Phase B: out = sampled @ w_out^T + b_out. Wave w owns n-tiles {2w, 2w+1};
//   per kcb: 1 ds_read_b128 A-frag + 2 direct B loads + 2 MFMA; acc[2].
#define SSTR 264
__global__ __launch_bounds__(512) void sample_out_kernel(
    const unsigned short* __restrict__ value,   // bf16 [b][s][h][32]
    const float* __restrict__ attnw, const float* __restrict__ locw,
    const short8* __restrict__ Wswz,            // wo_swz
    const float* __restrict__ bias,             // b_out
    float* __restrict__ Cv)                     // d_out fp32 [4800][256]
{
    const int rq0 = blockIdx.x << 4;
    const int tid = threadIdx.x;

    __shared__ int4           soff[16][96];
    __shared__ float4         swt[16][96];
    __shared__ unsigned short slds[16 * SSTR];  // sampled bf16, padded stride

    // setup: 1536 items (16 rq x 96 (h,lp)) across 512 threads
    for (int it = tid; it < 1536; it += 512) {
        int rsub = it / 96;
        int idx  = it - rsub * 96;
        int rq   = rq0 + rsub;
        int b    = rq / 300;
        int h  = idx / 12, lp = idx - h * 12;
        int l  = lp >> 2;
        int Wl = (l == 0) ? 80 : (l == 1) ? 40 : 20;        // H == W per level
        int s0 = (l == 0) ? 0  : (l == 1) ? 6400 : 8000;
        float lx = locw[(size_t)rq * 192 + h * 24 + lp * 2];
        float ly = locw[(size_t)rq * 192 + h * 24 + lp * 2 + 1];
        float aw = attnw[(size_t)rq * 96 + h * 12 + lp];
        float gx = lx * (float)Wl - 0.5f;
        float gy = ly * (float)Wl - 0.5f;
        float x0f = floorf(gx), y0f = floorf(gy);
        int   x0 = (int)x0f,   y0 = (int)y0f;
        float wx1 = gx - x0f, wx0 = 1.f - wx1;
        float wy1 = gy - y0f, wy0 = 1.f - wy1;
        int4 of; float4 wt;
#pragma unroll
        for (int j = 0; j < 4; ++j) {
            int x = x0 + (j & 1), y = y0 + (j >> 1);
            bool ok = (x >= 0) & (x < Wl) & (y >= 0) & (y < Wl);
            int idx2 = ok ? (((b * 8400 + s0 + y * Wl + x) * 8 + h) * 32) : 0;
            float w = ok ? aw * ((j & 1) ? wx1 : wx0) * ((j >> 1) ? wy1 : wy0) : 0.f;
            ((int*)&of)[j] = idx2;
            ((float*)&wt)[j] = w;
        }
        soff[rsub][idx] = of;
        swt[rsub][idx]  = wt;
    }
    __syncthreads();

    const int wave = tid >> 6;
    const int lane = tid & 63;
    {   // gather: wave w handles rq pair {2w, 2w+1}
        const int h  = lane >> 3;
        const int cq = (lane & 7) << 2;
        const int base = h * 12;
#pragma unroll
        for (int sub = 0; sub < 2; ++sub) {
            const int rsub = (wave << 1) + sub;
            float acc0 = 0.f, acc1 = 0.f, acc2 = 0.f, acc3 = 0.f;
#pragma unroll
            for (int lp = 0; lp < 12; ++lp) {
                int4   of = soff[rsub][base + lp];
                float4 wt = swt[rsub][base + lp];
#pragma unroll
                for (int j = 0; j < 4; ++j) {
                    int   o = ((const int*)&of)[j];
                    float w = ((const float*)&wt)[j];
                    uint2 u = *(const uint2*)(value + o + cq);   // 4 bf16 ch
                    union { unsigned int i; float f; } c0, c1, c2, c3;
                    c0.i = u.x << 16; c1.i = u.x & 0xFFFF0000u;
                    c2.i = u.y << 16; c3.i = u.y & 0xFFFF0000u;
                    acc0 += w * c0.f; acc1 += w * c1.f;
                    acc2 += w * c2.f; acc3 += w * c3.f;
                }
            }
            short4v s;
            s[0] = (short)f2bf(acc0);
            s[1] = (short)f2bf(acc1);
            s[2] = (short)f2bf(acc2);
            s[3] = (short)f2bf(acc3);
            *(short4v*)(slds + rsub * SSTR + h * 32 + cq) = s;
        }
    }
    __syncthreads();

    // Phase B: 16x256 GEMM. A-frag row = lane&15, k-chunk = (lane>>4)*8.
    f32x4 acc[2];
    acc[0] = (f32x4){0.f, 0.f, 0.f, 0.f};
    acc[1] = (f32x4){0.f, 0.f, 0.f, 0.f};

    const int am = lane & 15;
    const int kq = (lane >> 4) << 3;

#pragma unroll
    for (int kcb = 0; kcb < 8; ++kcb) {
        short8 a = *(const short8*)(slds + am * SSTR + (kcb << 5) + kq);
        const short8* bb = Wswz + (kcb << 10) + (wave << 7) + lane;
        acc[0] = __builtin_amdgcn_mfma_f32_16x16x32_bf16(a, bb[0],  acc[0], 0, 0, 0);
        acc[1] = __builtin_amdgcn_mfma_f32_16x16x32_bf16(a, bb[64], acc[1], 0, 0, 0);
    }

    const int ncol = lane & 15;
    const int rb   = rq0 + ((lane >> 4) << 2);
#pragma unroll
    for (int t = 0; t < 2; ++t) {
        int n = (wave << 5) + (t << 4) + ncol;
        float bv = bias[n];
#pragma unroll
        for (int r = 0; r < 4; ++r)
            Cv[(size_t)(rb + r) * 256 + n] = acc[t][r] + bv;
    }
}

extern "C" void kernel_launch(void* const* d_in, const int* in_sizes, int n_in,
                              void* d_out, int out_size, void* d_ws, size_t ws_size,
                              hipStream_t stream)
{
    const float* hidden  = (const float*)d_in[0];
    const float* enc     = (const float*)d_in[1];
    const float* refp    = (const float*)d_in[2];
    const float* w_value = (const float*)d_in[3];
    const float* b_value = (const float*)d_in[4];
    const float* w_off   = (const float*)d_in[5];
    const float* b_off   = (const float*)d_in[6];
    const float* w_attn  = (const float*)d_in[7];
    const float* b_attn  = (const float*)d_in[8];
    const float* w_out   = (const float*)d_in[9];
    const float* b_out   = (const float*)d_in[10];

    // ws layout: value 68,812,800 | (sampled slot unused since R14) |
    // attnw 1,843,200 | locw 3,686,400 | wv_swz | wo_swz | wp_swz
    char* ws = (char*)d_ws;
    unsigned short* value   = (unsigned short*)ws;
    float*          attnw   = (float*)(ws + 71270400);
    float*          locw    = (float*)(ws + 73113600);
    short8*         wv_swz  = (short8*)(ws + 76800000);
    short8*         wo_swz  = (short8*)(ws + 76931072);
    short8*         wp_swz  = (short8*)(ws + 77062144);

    prep_kernel<<<100, 256, 0, stream>>>(w_value, w_out, w_off, w_attn,        // K0
                                         wv_swz, wo_swz, wp_swz);
    gemm128<<<2100, 256, 0, stream>>>(enc, wv_swz, b_value, value);            // K1
    proj_gemm<<<300, 256, 0, stream>>>(hidden, wp_swz, b_off, b_attn,          // K2
                                       refp, attnw, locw);
    sample_out_kernel<<<300, 512, 0, stream>>>(value, attnw, locw,             // K34
                                               wo_swz, b_out, (float*)d_out);
}